// Round 1
// baseline (8574.586 us; speedup 1.0000x reference)
//
#include <hip/hip_runtime.h>

#define NPTS 256
#define NBATCH 64
#define INFD 1e18

__global__ void zero_out_kernel(float* out, int n) {
    int i = blockIdx.x * blockDim.x + threadIdx.x;
    if (i < n) out[i] = 0.0f;
}

__launch_bounds__(256, 1)
__global__ void hungarian_kernel(const float* __restrict__ pred,
                                 const float* __restrict__ target,
                                 float* __restrict__ out) {
    const int b    = blockIdx.x;
    const int tid  = threadIdx.x;
    const int lane = tid & 63;
    const int wave = tid >> 6;

    __shared__ float spx[NPTS], spy[NPTS], spz[NPTS];   // pred points
    __shared__ float stx[NPTS], sty[NPTS], stz[NPTS];   // target points
    __shared__ double su[NPTS + 1], sv[NPTS + 1], sminv[NPTS + 1];
    __shared__ int sp[NPTS + 1], sway[NPTS + 1];
    __shared__ int sused[NPTS + 1];
    __shared__ double redv[4];
    __shared__ int   redi[4];
    __shared__ float redf[4];

    // Stage points into LDS
    {
        const float* pb = pred   + (size_t)b * NPTS * 3;
        const float* tb = target + (size_t)b * NPTS * 3;
        spx[tid] = pb[tid * 3 + 0];
        spy[tid] = pb[tid * 3 + 1];
        spz[tid] = pb[tid * 3 + 2];
        stx[tid] = tb[tid * 3 + 0];
        sty[tid] = tb[tid * 3 + 1];
        stz[tid] = tb[tid * 3 + 2];
    }
    // Init potentials + matching (column j matched to row sp[j]; 0 = unmatched)
    su[tid] = 0.0; sv[tid] = 0.0; sp[tid] = 0;
    if (tid == 0) { su[NPTS] = 0.0; sv[NPTS] = 0.0; sp[NPTS] = 0; }
    __syncthreads();

    const int jcol = tid + 1;                 // this thread's column, 1..256
    const float tx = stx[jcol - 1], ty = sty[jcol - 1], tz = stz[jcol - 1];

    for (int i = 1; i <= NPTS; ++i) {
        // Row init
        sminv[jcol] = INFD;
        sused[jcol] = 0;
        if (tid == 0) { sused[0] = 0; sp[0] = i; sminv[0] = INFD; }
        __syncthreads();

        int j0   = 0;
        int jfin = 0;
        while (true) {
            if (tid == 0) sused[j0] = 1;
            __syncthreads();                  // B1: used[j0] visible
            const int    i0  = sp[j0];
            const double ui0 = su[i0];
            const float  px = spx[i0 - 1], py = spy[i0 - 1], pz = spz[i0 - 1];

            double myval;
            if (!sused[jcol]) {
                float dx = px - tx, dy = py - ty, dz = pz - tz;
                float d  = sqrtf(dx * dx + dy * dy + dz * dz);
                double cur = (double)d - ui0 - sv[jcol];
                double m   = sminv[jcol];
                if (cur < m) { m = cur; sminv[jcol] = cur; sway[jcol] = j0; }
                myval = m;
            } else {
                myval = INFD;
            }
            int myidx = jcol;

            // Wave argmin, first-index tie-break (matches np.argmin)
            #pragma unroll
            for (int off = 32; off > 0; off >>= 1) {
                double ov = __shfl_down(myval, off, 64);
                int    oi = __shfl_down(myidx, off, 64);
                if (ov < myval || (ov == myval && oi < myidx)) { myval = ov; myidx = oi; }
            }
            if (lane == 0) { redv[wave] = myval; redi[wave] = myidx; }
            __syncthreads();                  // B2: wave partials visible

            double delta = redv[0]; int j1 = redi[0];
            #pragma unroll
            for (int w = 1; w < 4; ++w) {
                double ov = redv[w]; int oi = redi[w];
                if (ov < delta || (ov == delta && oi < j1)) { delta = ov; j1 = oi; }
            }

            // Dual/slack update. u-scatter is conflict-free (matching injective).
            if (sused[jcol]) { su[sp[jcol]] += delta; sv[jcol] -= delta; }
            else             { sminv[jcol] -= delta; }
            if (tid == 0)    { su[sp[0]]   += delta; sv[0]    -= delta; }  // col 0 always used
            __syncthreads();                  // B3: updates visible for next iter

            if (sp[j1] == 0) { jfin = j1; break; }
            j0 = j1;
        }
        // Augment along alternating path (serial, short)
        if (tid == 0) {
            int j0a = jfin;
            while (j0a) { int j1a = sway[j0a]; sp[j0a] = sp[j1a]; j0a = j1a; }
        }
        __syncthreads();
    }

    // Matched cost: sum_j dist(pred[sp[j]-1], target[j-1])
    {
        int pr = sp[jcol] - 1;
        float dx = spx[pr] - tx, dy = spy[pr] - ty, dz = spz[pr] - tz;
        float s = sqrtf(dx * dx + dy * dy + dz * dz);
        #pragma unroll
        for (int off = 32; off > 0; off >>= 1) s += __shfl_down(s, off, 64);
        if (lane == 0) redf[wave] = s;
        __syncthreads();
        if (tid == 0) {
            float tot = redf[0] + redf[1] + redf[2] + redf[3];
            atomicAdd(out, tot / (float)NBATCH);
        }
    }
}

extern "C" void kernel_launch(void* const* d_in, const int* in_sizes, int n_in,
                              void* d_out, int out_size, void* d_ws, size_t ws_size,
                              hipStream_t stream) {
    const float* pred   = (const float*)d_in[0];
    const float* target = (const float*)d_in[1];
    float* out = (float*)d_out;

    zero_out_kernel<<<1, 64, 0, stream>>>(out, out_size);
    hungarian_kernel<<<NBATCH, 256, 0, stream>>>(pred, target, out);
}

// Round 2
// 6425.298 us; speedup vs baseline: 1.3345x; 1.3345x over previous
//
#include <hip/hip_runtime.h>

#define NPTS 256
#define NBATCH 64
#define BIGF 1e30f

// Monotonic fp32 -> u32 mapping (total order preserved), and inverse.
__device__ __forceinline__ unsigned int fkey(float f) {
    unsigned int u = __float_as_uint(f);
    return u ^ ((unsigned int)((int)u >> 31) | 0x80000000u);
}
__device__ __forceinline__ float funkey(unsigned int o) {
    unsigned int u = (o & 0x80000000u) ? (o ^ 0x80000000u) : ~o;
    return __uint_as_float(u);
}
__device__ __forceinline__ float rlane(float v, int l) {
    return __uint_as_float((unsigned int)__builtin_amdgcn_readlane((int)__float_as_uint(v), l));
}
__device__ __forceinline__ int rlanei(int v, int l) {
    return __builtin_amdgcn_readlane(v, l);
}

// Uniform-index select over a 4-element register array (no dynamic indexing -> no scratch).
#define SEL4(a, s) ((s) == 0 ? a[0] : (s) == 1 ? a[1] : (s) == 2 ? a[2] : a[3])

__global__ void zero_out_kernel(float* out, int n) {
    int i = blockIdx.x * blockDim.x + threadIdx.x;
    if (i < n) out[i] = 0.0f;
}

// One wave (64 lanes) per batch. Lane owns columns {lane, 64+lane, 128+lane, 192+lane}.
// JV / Hungarian in delta-accumulated (Dijkstra-absolute) form:
//   M[j] = min over tree rows i0 of (dist(i0,j) - (u0[i0] - D_at_entry) - v0[j])
//   selection: j1 = argmin over free j of M[j] (ties -> smallest col, == np.argmin)
//   D = M[j1]; dual commit deferred to end of search via T[j] = D when j used.
// No __syncthreads, no LDS: all state register-resident, cross-lane via readlane/shfl.
__launch_bounds__(64, 1)
__global__ void hungarian_wave(const float* __restrict__ pred,
                               const float* __restrict__ target,
                               float* __restrict__ out) {
    const int b    = blockIdx.x;
    const int lane = threadIdx.x;

    const float* pb = pred   + (size_t)b * NPTS * 3;
    const float* tb = target + (size_t)b * NPTS * 3;

    float prx[4], pry[4], prz[4];      // pred (row) points, distributed by row
    float tx[4], ty[4], tz[4];         // target (col) points, lane-owned
    float vv[4]  = {0.f, 0.f, 0.f, 0.f};   // dual v per column
    float upc[4] = {0.f, 0.f, 0.f, 0.f};   // u of the row matched to this column
    float Mv[4], Tv[4] = {0.f, 0.f, 0.f, 0.f};
    float rxc[4], ryc[4], rzc[4];      // coords of matched row, column-attached
    int   pc[4]  = {-1, -1, -1, -1};   // matched row per column (-1 = free)
    int   way[4] = {-1, -1, -1, -1};   // predecessor column in tree (-1 = root)

#pragma unroll
    for (int c = 0; c < 4; ++c) {
        int idx = c * 64 + lane;
        prx[c] = pb[idx * 3 + 0]; pry[c] = pb[idx * 3 + 1]; prz[c] = pb[idx * 3 + 2];
        tx[c]  = tb[idx * 3 + 0]; ty[c]  = tb[idx * 3 + 1]; tz[c]  = tb[idx * 3 + 2];
        rxc[c] = 0.f; ryc[c] = 0.f; rzc[c] = 0.f;
    }

    for (int i = 0; i < NPTS; ++i) {
#pragma unroll
        for (int c = 0; c < 4; ++c) Mv[c] = BIGF;
        int usedm = 0;

        // Root row i coords (i uniform -> scalar select + readlane)
        const int rsl = i >> 6, rln = i & 63;
        const float rootx = rlane(SEL4(prx, rsl), rln);
        const float rooty = rlane(SEL4(pry, rsl), rln);
        const float rootz = rlane(SEL4(prz, rsl), rln);

        float cpx = rootx, cpy = rooty, cpz = rootz;  // current tree-expansion row
        float ukey = 0.f;   // u0[i0] - D_at_entry (fresh row: u=0, D=0)
        float D = 0.f;
        int j0 = -1;        // predecessor column (root marker)
        int jfin = 0;

        while (true) {
            // Slack update for free columns against row i0 (all register math)
#pragma unroll
            for (int c = 0; c < 4; ++c) {
                if (!((usedm >> c) & 1)) {
                    float dx = cpx - tx[c], dy = cpy - ty[c], dz = cpz - tz[c];
                    float d = sqrtf(dx * dx + dy * dy + dz * dz);
                    float cand = d - ukey - vv[c];
                    if (cand < Mv[c]) { Mv[c] = cand; way[c] = j0; }
                }
            }

            // Lexicographic (value, col) argmin over free columns: u64 key butterfly
            unsigned long long k = ~0ull;
#pragma unroll
            for (int c = 0; c < 4; ++c) {
                if (!((usedm >> c) & 1)) {
                    unsigned long long kc = ((unsigned long long)fkey(Mv[c]) << 32)
                                          | (unsigned int)(c * 64 + lane);
                    if (kc < k) k = kc;
                }
            }
#pragma unroll
            for (int off = 1; off < 64; off <<= 1) {
                unsigned long long ko = __shfl_xor(k, off, 64);
                if (ko < k) k = ko;
            }
            const int j1 = __builtin_amdgcn_readfirstlane((int)(unsigned int)(k & 0xffffffffu));
            D = funkey((unsigned int)__builtin_amdgcn_readfirstlane((int)(unsigned int)(k >> 32)));
            const int osl = j1 >> 6, oln = j1 & 63;

            // Fetch matched row of selected column (uniform lane -> v_readlane)
            const int pj = rlanei(SEL4(pc, osl), oln);
            if (pj < 0) { jfin = j1; break; }   // free column reached -> augmenting path found

            const float uj  = rlane(SEL4(upc, osl), oln);
            const float nrx = rlane(SEL4(rxc, osl), oln);
            const float nry = rlane(SEL4(ryc, osl), oln);
            const float nrz = rlane(SEL4(rzc, osl), oln);

            // Mark used + record T (owner lane only; osl uniform)
#pragma unroll
            for (int c = 0; c < 4; ++c)
                if (c == osl && lane == oln) { usedm |= (1 << c); Tv[c] = D; }

            cpx = nrx; cpy = nry; cpz = nrz;
            ukey = uj - D;
            j0 = j1;
        }

        // Commit duals: each used column j received deltas summing to D_final - T[j]
#pragma unroll
        for (int c = 0; c < 4; ++c) {
            if ((usedm >> c) & 1) {
                float amt = D - Tv[c];
                vv[c]  -= amt;
                upc[c] += amt;
            }
        }

        // Augment along the alternating path (p and its attached u/coords travel together)
        int jc = jfin;
        while (true) {
            const int osl = jc >> 6, oln = jc & 63;
            const int jw = rlanei(SEL4(way, osl), oln);
            int np_; float nup, nrx, nry, nrz;
            if (jw < 0) {   // root: insert row i with u = D_final
                np_ = i; nup = D; nrx = rootx; nry = rooty; nrz = rootz;
            } else {
                const int wsl = jw >> 6, wln = jw & 63;
                np_ = rlanei(SEL4(pc,  wsl), wln);
                nup = rlane(SEL4(upc, wsl), wln);
                nrx = rlane(SEL4(rxc, wsl), wln);
                nry = rlane(SEL4(ryc, wsl), wln);
                nrz = rlane(SEL4(rzc, wsl), wln);
            }
#pragma unroll
            for (int c = 0; c < 4; ++c)
                if (c == osl && lane == oln) {
                    pc[c] = np_; upc[c] = nup;
                    rxc[c] = nrx; ryc[c] = nry; rzc[c] = nrz;
                }
            if (jw < 0) break;
            jc = jw;
        }
    }

    // Matched cost: coords of matched row are already column-attached
    float s = 0.f;
#pragma unroll
    for (int c = 0; c < 4; ++c) {
        float dx = rxc[c] - tx[c], dy = ryc[c] - ty[c], dz = rzc[c] - tz[c];
        s += sqrtf(dx * dx + dy * dy + dz * dz);
    }
#pragma unroll
    for (int off = 1; off < 64; off <<= 1) s += __shfl_xor(s, off, 64);
    if (lane == 0) atomicAdd(out, s / (float)NBATCH);
}

extern "C" void kernel_launch(void* const* d_in, const int* in_sizes, int n_in,
                              void* d_out, int out_size, void* d_ws, size_t ws_size,
                              hipStream_t stream) {
    const float* pred   = (const float*)d_in[0];
    const float* target = (const float*)d_in[1];
    float* out = (float*)d_out;

    zero_out_kernel<<<1, 64, 0, stream>>>(out, out_size);
    hungarian_wave<<<NBATCH, 64, 0, stream>>>(pred, target, out);
}

// Round 3
// 3242.577 us; speedup vs baseline: 2.6444x; 1.9815x over previous
//
#include <hip/hip_runtime.h>

#define NPTS 256
#define NBATCH 64
#define BIGF 1e30f

__device__ __forceinline__ float rlane(float v, int l) {
    return __uint_as_float((unsigned int)__builtin_amdgcn_readlane((int)__float_as_uint(v), l));
}
__device__ __forceinline__ int rlanei(int v, int l) {
    return __builtin_amdgcn_readlane(v, l);
}

// One DPP min step: result = min(v, dpp_shuffle(v)); invalid lanes keep v (old operand).
#define DPP_FMIN(v, ctrl) \
    fminf(v, __int_as_float(__builtin_amdgcn_update_dpp( \
        __float_as_int(v), __float_as_int(v), (ctrl), 0xf, 0xf, false)))

// Full-wave min via row_shr 1/2/4/8 + row_bcast15 + row_bcast31; valid in lane 63.
__device__ __forceinline__ float wave_fmin_bcast(float v) {
    v = DPP_FMIN(v, 0x111);   // row_shr:1
    v = DPP_FMIN(v, 0x112);   // row_shr:2
    v = DPP_FMIN(v, 0x114);   // row_shr:4
    v = DPP_FMIN(v, 0x118);   // row_shr:8
    v = DPP_FMIN(v, 0x142);   // row_bcast:15
    v = DPP_FMIN(v, 0x143);   // row_bcast:31
    return rlane(v, 63);      // uniform (SGPR) broadcast
}

__global__ void zero_out_kernel(float* out, int n) {
    int i = blockIdx.x * blockDim.x + threadIdx.x;
    if (i < n) out[i] = 0.0f;
}

// One wave per batch. Lane owns columns {lane, 64+lane, 128+lane, 192+lane}.
// JV with column-reduction greedy init + delta-accumulated Dijkstra searches.
// All state register-resident; cross-lane via readlane/DPP/ballot. No LDS, no barriers.
__launch_bounds__(64, 1)
__global__ void hungarian_wave(const float* __restrict__ pred,
                               const float* __restrict__ target,
                               float* __restrict__ out) {
    const int b    = blockIdx.x;
    const int lane = threadIdx.x;

    const float* pb = pred   + (size_t)b * NPTS * 3;
    const float* tb = target + (size_t)b * NPTS * 3;

    float prx[4], pry[4], prz[4];      // pred (row) points, row = c*64+lane
    float tx[4], ty[4], tz[4];         // target (col) points, col = c*64+lane
    float vv[4], upc[4], Mv[4];
    float rxc[4], ryc[4], rzc[4];      // matched row coords, column-attached
    int   pc[4]  = {-1, -1, -1, -1};   // matched row per column (-1 = free)
    int   way[4];

#pragma unroll
    for (int c = 0; c < 4; ++c) {
        int idx = c * 64 + lane;
        prx[c] = pb[idx * 3 + 0]; pry[c] = pb[idx * 3 + 1]; prz[c] = pb[idx * 3 + 2];
        tx[c]  = tb[idx * 3 + 0]; ty[c]  = tb[idx * 3 + 1]; tz[c]  = tb[idx * 3 + 2];
        upc[c] = 0.f; rxc[c] = 0.f; ryc[c] = 0.f; rzc[c] = 0.f;
    }

    // ---- Phase 1a: column reduction. vv[c] = min_r d(r, col), colrow = argmin ----
    float colmin[4] = {BIGF, BIGF, BIGF, BIGF};
    int   colrow[4] = {0, 0, 0, 0};
#pragma unroll
    for (int rs = 0; rs < 4; ++rs) {
        for (int rl = 0; rl < 64; ++rl) {
            float bx = rlane(prx[rs], rl), by = rlane(pry[rs], rl), bz = rlane(prz[rs], rl);
            int r = rs * 64 + rl;
#pragma unroll
            for (int c = 0; c < 4; ++c) {
                float dx = bx - tx[c], dy = by - ty[c], dz = bz - tz[c];
                float d = sqrtf(dx * dx + dy * dy + dz * dz);
                if (d < colmin[c]) { colmin[c] = d; colrow[c] = r; }
            }
        }
    }
#pragma unroll
    for (int c = 0; c < 4; ++c) vv[c] = colmin[c];   // v[j] = column min (all cols)

    // ---- Phase 1b: greedy matching — first column (ascending j) claims its argmin row ----
    unsigned long long tk0 = 0ull, tk1 = 0ull, tk2 = 0ull, tk3 = 0ull;  // rows taken
#pragma unroll
    for (int cs = 0; cs < 4; ++cs) {
        for (int l = 0; l < 64; ++l) {
            int r = rlanei(colrow[cs], l);
            int rs = r >> 6, rl2 = r & 63;
            unsigned long long bit = 1ull << rl2;
            bool free_row;
            if      (rs == 0) { free_row = !(tk0 & bit); if (free_row) tk0 |= bit; }
            else if (rs == 1) { free_row = !(tk1 & bit); if (free_row) tk1 |= bit; }
            else if (rs == 2) { free_row = !(tk2 & bit); if (free_row) tk2 |= bit; }
            else              { free_row = !(tk3 & bit); if (free_row) tk3 |= bit; }
            if (free_row) {
                float bx, by, bz;
                switch (rs) {
                    case 0: bx = rlane(prx[0], rl2); by = rlane(pry[0], rl2); bz = rlane(prz[0], rl2); break;
                    case 1: bx = rlane(prx[1], rl2); by = rlane(pry[1], rl2); bz = rlane(prz[1], rl2); break;
                    case 2: bx = rlane(prx[2], rl2); by = rlane(pry[2], rl2); bz = rlane(prz[2], rl2); break;
                    default: bx = rlane(prx[3], rl2); by = rlane(pry[3], rl2); bz = rlane(prz[3], rl2); break;
                }
                if (lane == l) {
                    pc[cs] = r; upc[cs] = 0.f;
                    rxc[cs] = bx; ryc[cs] = by; rzc[cs] = bz;
                }
            }
        }
    }
    const unsigned long long init0 = tk0, init1 = tk1, init2 = tk2, init3 = tk3;

    // ---- Phase 2: shortest-path searches for rows not matched by greedy init ----
    float D = 0.f;
#pragma unroll
    for (int is = 0; is < 4; ++is) {
        unsigned long long initm = (is == 0) ? init0 : (is == 1) ? init1 : (is == 2) ? init2 : init3;
        for (int il = 0; il < 64; ++il) {
            if ((initm >> il) & 1ull) continue;   // row matched by greedy init
            const int i = is * 64 + il;

            const float rootx = rlane(prx[is], il);
            const float rooty = rlane(pry[is], il);
            const float rootz = rlane(prz[is], il);

#pragma unroll
            for (int c = 0; c < 4; ++c) Mv[c] = BIGF;
            int usedm = 0;

            float cpx = rootx, cpy = rooty, cpz = rootz;
            float ukey = 0.f;    // u0[i0] - D_at_entry
            int j0 = -1;
            int jfin = 0;

            while (true) {
                // Slack update + local (value, col) min over this lane's free columns
                float lval = BIGF; int lcol = 0;
#pragma unroll
                for (int c = 0; c < 4; ++c) {
                    if (!((usedm >> c) & 1)) {
                        float dx = cpx - tx[c], dy = cpy - ty[c], dz = cpz - tz[c];
                        float d = sqrtf(dx * dx + dy * dy + dz * dz);
                        float cand = d - ukey - vv[c];
                        if (cand < Mv[c]) { Mv[c] = cand; way[c] = j0; }
                        if (Mv[c] < lval) { lval = Mv[c]; lcol = c * 64 + lane; }
                    }
                }

                // Global min (VALU-only DPP chain) + argmin via ballot
                const float gmin = wave_fmin_bcast(lval);
                unsigned long long msk = __ballot(lval == gmin);
                const int flane = (int)__builtin_ctzll(msk);
                const int j1 = rlanei(lcol, flane);
                const int osl = j1 >> 6, oln = j1 & 63;

                // Matched row of selected column (uniform -> scalar branch + readlane)
                int pj;
                switch (osl) {
                    case 0: pj = rlanei(pc[0], oln); break;
                    case 1: pj = rlanei(pc[1], oln); break;
                    case 2: pj = rlanei(pc[2], oln); break;
                    default: pj = rlanei(pc[3], oln); break;
                }
                if (pj < 0) { jfin = j1; D = gmin; break; }

                float uj, nx, ny, nz;
                switch (osl) {
                    case 0: uj = rlane(upc[0], oln); nx = rlane(rxc[0], oln); ny = rlane(ryc[0], oln); nz = rlane(rzc[0], oln); break;
                    case 1: uj = rlane(upc[1], oln); nx = rlane(rxc[1], oln); ny = rlane(ryc[1], oln); nz = rlane(rzc[1], oln); break;
                    case 2: uj = rlane(upc[2], oln); nx = rlane(rxc[2], oln); ny = rlane(ryc[2], oln); nz = rlane(rzc[2], oln); break;
                    default: uj = rlane(upc[3], oln); nx = rlane(rxc[3], oln); ny = rlane(ryc[3], oln); nz = rlane(rzc[3], oln); break;
                }

                // Mark used; deferred-dual trick: +gmin now, -D_final at commit
#pragma unroll
                for (int c = 0; c < 4; ++c)
                    if (c == osl && lane == oln) {
                        usedm |= (1 << c);
                        vv[c] += gmin;
                        upc[c] -= gmin;
                    }

                cpx = nx; cpy = ny; cpz = nz;
                ukey = uj - gmin;
                j0 = j1;
            }

            // Commit duals for used columns: net amount = D_final - D_at_use
#pragma unroll
            for (int c = 0; c < 4; ++c)
                if ((usedm >> c) & 1) { vv[c] -= D; upc[c] += D; }

            // Augment along alternating path
            int jc = jfin;
            while (true) {
                const int osl = jc >> 6, oln = jc & 63;
                int jw;
                switch (osl) {
                    case 0: jw = rlanei(way[0], oln); break;
                    case 1: jw = rlanei(way[1], oln); break;
                    case 2: jw = rlanei(way[2], oln); break;
                    default: jw = rlanei(way[3], oln); break;
                }
                int np_; float nup, nrx, nry, nrz;
                if (jw < 0) {   // root: insert row i with u = D_final
                    np_ = i; nup = D; nrx = rootx; nry = rooty; nrz = rootz;
                } else {
                    const int wsl = jw >> 6, wln = jw & 63;
                    switch (wsl) {
                        case 0: np_ = rlanei(pc[0], wln); nup = rlane(upc[0], wln); nrx = rlane(rxc[0], wln); nry = rlane(ryc[0], wln); nrz = rlane(rzc[0], wln); break;
                        case 1: np_ = rlanei(pc[1], wln); nup = rlane(upc[1], wln); nrx = rlane(rxc[1], wln); nry = rlane(ryc[1], wln); nrz = rlane(rzc[1], wln); break;
                        case 2: np_ = rlanei(pc[2], wln); nup = rlane(upc[2], wln); nrx = rlane(rxc[2], wln); nry = rlane(ryc[2], wln); nrz = rlane(rzc[2], wln); break;
                        default: np_ = rlanei(pc[3], wln); nup = rlane(upc[3], wln); nrx = rlane(rxc[3], wln); nry = rlane(ryc[3], wln); nrz = rlane(rzc[3], wln); break;
                    }
                }
#pragma unroll
                for (int c = 0; c < 4; ++c)
                    if (c == osl && lane == oln) {
                        pc[c] = np_; upc[c] = nup;
                        rxc[c] = nrx; ryc[c] = nry; rzc[c] = nrz;
                    }
                if (jw < 0) break;
                jc = jw;
            }
        }
    }

    // ---- Matched cost sum (matched row coords are column-attached) ----
    float s = 0.f;
#pragma unroll
    for (int c = 0; c < 4; ++c) {
        float dx = rxc[c] - tx[c], dy = ryc[c] - ty[c], dz = rzc[c] - tz[c];
        s += sqrtf(dx * dx + dy * dy + dz * dz);
    }
#pragma unroll
    for (int off = 1; off < 64; off <<= 1) s += __shfl_xor(s, off, 64);
    if (lane == 0) atomicAdd(out, s / (float)NBATCH);
}

extern "C" void kernel_launch(void* const* d_in, const int* in_sizes, int n_in,
                              void* d_out, int out_size, void* d_ws, size_t ws_size,
                              hipStream_t stream) {
    const float* pred   = (const float*)d_in[0];
    const float* target = (const float*)d_in[1];
    float* out = (float*)d_out;

    zero_out_kernel<<<1, 64, 0, stream>>>(out, out_size);
    hungarian_wave<<<NBATCH, 64, 0, stream>>>(pred, target, out);
}